// Round 5
// baseline (105.857 us; speedup 1.0000x reference)
//
#include <hip/hip_runtime.h>
#include <math.h>

// AUC surrogate loss = (1/(P*N)) * sum_{i:pos,j:neg} sigmoid(p_j - p_i)
//
// R5: the sum depends only on pairwise differences -> cross-correlation of
// the class histograms.  Deposit preds on a 2049-node grid over [-12,12]
// with linear-interp weights; then
//   sum = SUM_k SUM_l hP[k] * hN[l] * sigmoid((l-k)*delta)
// which is the exact bilinear interpolation of sigmoid at the true (p_i,p_j).
// Error <= delta^2/8 * 2*max|f''| ~ 3e-6  (threshold 9.9e-3).
// Work: 67M pair-sigmoids -> 4.2M fma against an LDS S-table. P,N exact.
// 3 dispatches, zero global atomics, zero memsets (plain-store ws only).

#define NODES 2049                 // grid nodes (2048 intervals)
#define NPAD  2052                 // padded hist stride
#define SLEN  4097                 // S[m+2048], m = k-l in [-2048,2048]
#define KC    8                    // k's per conv block

static constexpr float LO    = -12.0f;
static constexpr float DELTA = 24.0f / 2048.0f;
static constexpr float INVD  = 2048.0f / 24.0f;
static constexpr float LOG2E = 1.4426950408889634f;

// ---- histogram: one block, LDS float atomics, linear-interp deposit --------

__global__ __launch_bounds__(1024)
void hist_k(const float* __restrict__ pred, const int* __restrict__ yt, int B,
            float* __restrict__ g_hP, float* __restrict__ g_hN,
            int* __restrict__ g_P) {
    __shared__ float h[2 * NPAD];
    const int t = threadIdx.x;
    for (int i = t; i < 2 * NPAD; i += 1024) h[i] = 0.f;
    __syncthreads();

    int cp = 0;
    for (int e = t; e < B; e += 1024) {
        float p = pred[e];
        int   c = yt[e];
        float x = (p - LO) * INVD;
        x = fminf(fmaxf(x, 0.f), 2047.999f);   // 8-sigma grid; clamp is no-op in practice
        int   k = (int)x;
        float f = x - (float)k;
        int base = (c == 1) ? 0 : NPAD;
        cp += (c == 1);
        atomicAdd(&h[base + k],     1.f - f);
        atomicAdd(&h[base + k + 1], f);
    }
    __syncthreads();

    for (int i = t; i < NODES; i += 1024) {
        g_hP[i] = h[i];
        g_hN[i] = h[NPAD + i];
    }

    #pragma unroll
    for (int off = 32; off; off >>= 1) cp += __shfl_down(cp, off, 64);
    __shared__ int wc[16];
    if ((t & 63) == 0) wc[t >> 6] = cp;
    __syncthreads();
    if (t == 0) {
        int s = 0;
        #pragma unroll
        for (int k = 0; k < 16; ++k) s += wc[k];
        *g_P = s;                              // N = B - P
    }
}

// ---- correlation: 257 blocks x 256 thr over 2049 x 2049 node pairs ---------

__global__ __launch_bounds__(256)
void conv_k(const float* __restrict__ g_hP, const float* __restrict__ g_hN,
            float* __restrict__ partial) {
    __shared__ float sS[SLEN];
    __shared__ float sN[NODES];
    const int t = threadIdx.x;
    const int b = blockIdx.x;

    for (int i = t; i < NODES; i += 256) sN[i] = g_hN[i];
    for (int i = t; i < SLEN; i += 256) {
        // S[i] = sigmoid(-(i-2048)*DELTA) = 1/(1+e^{(i-2048)*DELTA})
        float d = (float)(i - 2048) * DELTA;
        float e = __builtin_amdgcn_exp2f(d * LOG2E);
        sS[i] = __builtin_amdgcn_rcpf(1.f + e);
    }
    __syncthreads();

    float acc = 0.f;
    #pragma unroll
    for (int kk = 0; kk < KC; ++kk) {
        int k = b * KC + kk;
        if (k < NODES) {
            float hPk = g_hP[k];               // wave-uniform scalar
            if (hPk != 0.f) {                  // ~60% of nodes empty: skip
                const float* Sk = &sS[k + 2048];
                for (int l = t; l < NODES; l += 256)
                    acc += hPk * (sN[l] * Sk[-l]);   // stride-1 LDS, no conflicts
            }
        }
    }

    #pragma unroll
    for (int off = 32; off; off >>= 1) acc += __shfl_down(acc, off, 64);
    __shared__ float wa[4];
    if ((t & 63) == 0) wa[t >> 6] = acc;
    __syncthreads();
    if (t == 0) partial[b] = (wa[0] + wa[1]) + (wa[2] + wa[3]);
}

// ---- finalize ---------------------------------------------------------------

__global__ __launch_bounds__(256)
void reduce_k(const float* __restrict__ partial, int nPart,
              const int* __restrict__ g_P, int B, float* __restrict__ out) {
    const int t = threadIdx.x;
    double s = 0.0;
    for (int i = t; i < nPart; i += 256) s += (double)partial[i];
    #pragma unroll
    for (int off = 32; off; off >>= 1) s += __shfl_down(s, off, 64);
    __shared__ double wa[4];
    if ((t & 63) == 0) wa[t >> 6] = s;
    __syncthreads();
    if (t == 0) {
        double S = (wa[0] + wa[1]) + (wa[2] + wa[3]);
        double P = (double)(*g_P);
        double N = (double)B - P;
        out[0] = (float)(S / (P * N));
    }
}

extern "C" void kernel_launch(void* const* d_in, const int* in_sizes, int n_in,
                              void* d_out, int out_size, void* d_ws, size_t ws_size,
                              hipStream_t stream) {
    const float* pred = (const float*)d_in[0];
    const int*   yt   = (const int*)d_in[1];
    const int B = in_sizes[0];
    float* out = (float*)d_out;

    float* g_hP = (float*)d_ws;            // NPAD floats
    float* g_hN = g_hP + NPAD;             // NPAD floats
    int*   g_P  = (int*)(g_hN + NPAD);
    float* part = (float*)(g_P + 64);      // 257 floats

    const int nBlk = (NODES + KC - 1) / KC;   // 257

    hist_k<<<1, 1024, 0, stream>>>(pred, yt, B, g_hP, g_hN, g_P);
    conv_k<<<nBlk, 256, 0, stream>>>(g_hP, g_hN, part);
    reduce_k<<<1, 256, 0, stream>>>(part, nBlk, g_P, B, out);
}

// Round 6
// 72.363 us; speedup vs baseline: 1.4629x; 1.4629x over previous
//
#include <hip/hip_runtime.h>
#include <math.h>

// AUC surrogate loss = (1/(P*N)) * sum_{i:pos,j:neg} sigmoid(p_j - p_i)
//
// R6: histogram cross-correlation (R5) with the hist DISTRIBUTED over 16
// blocks (R5's single-block hist serialized 32768 LDS-atomic ops through one
// CU's LDS pipe = 44us).  Each block deposits its 1024 elements into a
// private LDS hist (linear-interp weights) and plain-stores the copy to ws;
// conv_k merges the 16 copies on load.  Zero global atomics, zero memsets.
//   sum = SUM_k SUM_l hP[k] * hN[l] * sigmoid((l-k)*delta)   (exact bilinear
// interp of sigmoid; err ~3e-6 << 9.9e-3 threshold).  P,N counted exactly.

#define NODES 2049                 // grid nodes (2048 intervals)
#define NPAD  2052                 // padded hist stride
#define SLEN  4097                 // S[m+2048], m = k-l in [-2048,2048]
#define KC    8                    // k's per conv block
#define HB    16                   // histogram blocks

static constexpr float LO    = -12.0f;
static constexpr float DELTA = 24.0f / 2048.0f;
static constexpr float INVD  = 2048.0f / 24.0f;
static constexpr float LOG2E = 1.4426950408889634f;

// ---- histogram: HB blocks, private LDS hists, plain-store copies -----------

__global__ __launch_bounds__(1024)
void hist_k(const float* __restrict__ pred, const int* __restrict__ yt, int B,
            float* __restrict__ g_h /* HB x 2 x NPAD */,
            int* __restrict__ g_Pc /* HB */) {
    __shared__ float h[2 * NPAD];
    const int t = threadIdx.x;
    const int b = blockIdx.x;

    for (int i = t; i < 2 * NPAD; i += 1024) h[i] = 0.f;
    __syncthreads();

    int cp = 0;
    for (int e = b * 1024 + t; e < B; e += HB * 1024) {
        float p = pred[e];
        int   c = yt[e];
        float x = (p - LO) * INVD;
        x = fminf(fmaxf(x, 0.f), 2047.999f);   // 8-sigma grid; clamp no-op in practice
        int   k = (int)x;
        float f = x - (float)k;
        int base = (c == 1) ? 0 : NPAD;
        cp += (c == 1);
        atomicAdd(&h[base + k],     1.f - f);
        atomicAdd(&h[base + k + 1], f);
    }
    __syncthreads();

    float* dst = g_h + (size_t)b * 2 * NPAD;
    for (int i = t; i < NODES; i += 1024) {
        dst[i]        = h[i];
        dst[NPAD + i] = h[NPAD + i];
    }

    #pragma unroll
    for (int off = 32; off; off >>= 1) cp += __shfl_down(cp, off, 64);
    __shared__ int wc[16];
    if ((t & 63) == 0) wc[t >> 6] = cp;
    __syncthreads();
    if (t == 0) {
        int s = 0;
        #pragma unroll
        for (int k = 0; k < 16; ++k) s += wc[k];
        g_Pc[b] = s;
    }
}

// ---- correlation: 257 blocks x 256 thr over 2049 x 2049 node pairs ---------

__global__ __launch_bounds__(256)
void conv_k(const float* __restrict__ g_h, float* __restrict__ partial) {
    __shared__ float sS[SLEN];
    __shared__ float sN[NODES];
    const int t = threadIdx.x;
    const int bk = blockIdx.x;

    for (int i = t; i < NODES; i += 256) {        // merge 16 hN copies (L2-hot)
        float s = 0.f;
        #pragma unroll
        for (int b = 0; b < HB; ++b) s += g_h[(size_t)b * 2 * NPAD + NPAD + i];
        sN[i] = s;
    }
    for (int i = t; i < SLEN; i += 256) {
        // S[i] = sigmoid(-(i-2048)*DELTA) = 1/(1+e^{(i-2048)*DELTA})
        float d = (float)(i - 2048) * DELTA;
        float e = __builtin_amdgcn_exp2f(d * LOG2E);
        sS[i] = __builtin_amdgcn_rcpf(1.f + e);
    }
    __syncthreads();

    float acc = 0.f;
    #pragma unroll
    for (int kk = 0; kk < KC; ++kk) {
        int k = bk * KC + kk;
        if (k < NODES) {
            float hPk = 0.f;                      // merge 16 hP[k] scalars
            #pragma unroll
            for (int b = 0; b < HB; ++b) hPk += g_h[(size_t)b * 2 * NPAD + k];
            if (hPk != 0.f) {
                const float* Sk = &sS[k + 2048];
                for (int l = t; l < NODES; l += 256)
                    acc += hPk * (sN[l] * Sk[-l]);   // stride-1 LDS, conflict-free
            }
        }
    }

    #pragma unroll
    for (int off = 32; off; off >>= 1) acc += __shfl_down(acc, off, 64);
    __shared__ float wa[4];
    if ((t & 63) == 0) wa[t >> 6] = acc;
    __syncthreads();
    if (t == 0) partial[bk] = (wa[0] + wa[1]) + (wa[2] + wa[3]);
}

// ---- finalize ---------------------------------------------------------------

__global__ __launch_bounds__(256)
void reduce_k(const float* __restrict__ partial, int nPart,
              const int* __restrict__ g_Pc, int B, float* __restrict__ out) {
    const int t = threadIdx.x;
    double s = 0.0;
    for (int i = t; i < nPart; i += 256) s += (double)partial[i];
    int cp = 0;
    if (t < HB) cp = g_Pc[t];
    #pragma unroll
    for (int off = 32; off; off >>= 1) {
        s  += __shfl_down(s, off, 64);
        cp += __shfl_down(cp, off, 64);
    }
    __shared__ double wa[4];
    __shared__ int    wp[4];
    if ((t & 63) == 0) { wa[t >> 6] = s; wp[t >> 6] = cp; }
    __syncthreads();
    if (t == 0) {
        double S = (wa[0] + wa[1]) + (wa[2] + wa[3]);
        double P = (double)(wp[0] + wp[1] + wp[2] + wp[3]);
        double N = (double)B - P;
        out[0] = (float)(S / (P * N));
    }
}

extern "C" void kernel_launch(void* const* d_in, const int* in_sizes, int n_in,
                              void* d_out, int out_size, void* d_ws, size_t ws_size,
                              hipStream_t stream) {
    const float* pred = (const float*)d_in[0];
    const int*   yt   = (const int*)d_in[1];
    const int B = in_sizes[0];
    float* out = (float*)d_out;

    float* g_h  = (float*)d_ws;                       // HB*2*NPAD floats
    int*   g_Pc = (int*)(g_h + (size_t)HB * 2 * NPAD);
    float* part = (float*)(g_Pc + 64);                // 257 floats

    const int nBlk = (NODES + KC - 1) / KC;           // 257

    hist_k<<<HB, 1024, 0, stream>>>(pred, yt, B, g_h, g_Pc);
    conv_k<<<nBlk, 256, 0, stream>>>(g_h, part);
    reduce_k<<<1, 256, 0, stream>>>(part, nBlk, g_Pc, B, out);
}